// Round 1
// baseline (344.308 us; speedup 1.0000x reference)
//
#include <hip/hip_runtime.h>

#define T_LEN 4000000
#define T4 (T_LEN / 4)

// ---------------------------------------------------------------------------
// Pass 1: statistics reduction over the 3 position rows.
// Accumulate Sx,Sy,Sz, Sxx,Syy,Szz, Sxy,Sxz,Syz in f64 (f32 horizontal dot
// inside each float4 chunk; f64 across chunks -> cov error ~1e-10, far below
// the ~1e-3 eigen-gap of this near-isotropic covariance).
// ---------------------------------------------------------------------------
__global__ void stats_kernel(const float* __restrict__ x, double* __restrict__ sums) {
    const float4* __restrict__ r0 = reinterpret_cast<const float4*>(x);
    const float4* __restrict__ r1 = reinterpret_cast<const float4*>(x + (size_t)T_LEN);
    const float4* __restrict__ r2 = reinterpret_cast<const float4*>(x + 2 * (size_t)T_LEN);

    double s[9];
#pragma unroll
    for (int k = 0; k < 9; ++k) s[k] = 0.0;

    const int stride = gridDim.x * blockDim.x;
    for (int i = blockIdx.x * blockDim.x + threadIdx.x; i < T4; i += stride) {
        float4 a = r0[i];
        float4 b = r1[i];
        float4 c = r2[i];
        s[0] += (double)(a.x + a.y + a.z + a.w);
        s[1] += (double)(b.x + b.y + b.z + b.w);
        s[2] += (double)(c.x + c.y + c.z + c.w);
        s[3] += (double)(a.x * a.x + a.y * a.y + a.z * a.z + a.w * a.w);
        s[4] += (double)(b.x * b.x + b.y * b.y + b.z * b.z + b.w * b.w);
        s[5] += (double)(c.x * c.x + c.y * c.y + c.z * c.z + c.w * c.w);
        s[6] += (double)(a.x * b.x + a.y * b.y + a.z * b.z + a.w * b.w);
        s[7] += (double)(a.x * c.x + a.y * c.y + a.z * c.z + a.w * c.w);
        s[8] += (double)(b.x * c.x + b.y * c.y + b.z * c.z + b.w * c.w);
    }

    // wave64 butterfly reduce
#pragma unroll
    for (int off = 32; off > 0; off >>= 1) {
#pragma unroll
        for (int k = 0; k < 9; ++k) s[k] += __shfl_down(s[k], off, 64);
    }

    __shared__ double lds[4][9];  // 256 threads = 4 waves
    const int lane = threadIdx.x & 63;
    const int wave = threadIdx.x >> 6;
    if (lane == 0) {
#pragma unroll
        for (int k = 0; k < 9; ++k) lds[wave][k] = s[k];
    }
    __syncthreads();
    if (threadIdx.x == 0) {
#pragma unroll
        for (int k = 0; k < 9; ++k) {
            double t = lds[0][k] + lds[1][k] + lds[2][k] + lds[3][k];
            atomicAdd(&sums[k], t);  // f64 HW atomic on gfx950
        }
    }
}

// ---------------------------------------------------------------------------
// Pass 2: single-thread finalize. cov -> largest-eig eigenvector (analytic,
// f64) -> quaternion sign fix -> basis + refPos into workspace floats.
// ---------------------------------------------------------------------------
__global__ void finalize_kernel(const float* __restrict__ x,
                                const float* __restrict__ ref_axis,
                                const double* __restrict__ sums,
                                float* __restrict__ bp) {
    if (threadIdx.x != 0 || blockIdx.x != 0) return;

    const double T = (double)T_LEN;
    const double mu0 = sums[0] / T, mu1 = sums[1] / T, mu2 = sums[2] / T;
    const double d = 1.0 / (T - 1.0);
    const double a00 = (sums[3] - T * mu0 * mu0) * d;
    const double a11 = (sums[4] - T * mu1 * mu1) * d;
    const double a22 = (sums[5] - T * mu2 * mu2) * d;
    const double a01 = (sums[6] - T * mu0 * mu1) * d;
    const double a02 = (sums[7] - T * mu0 * mu2) * d;
    const double a12 = (sums[8] - T * mu1 * mu2) * d;

    // Largest eigenvalue via trigonometric method (Smith), f64.
    const double q = (a00 + a11 + a22) / 3.0;
    const double p1 = a01 * a01 + a02 * a02 + a12 * a12;
    const double b00 = a00 - q, b11 = a11 - q, b22 = a22 - q;
    const double p2 = b00 * b00 + b11 * b11 + b22 * b22 + 2.0 * p1;

    double vx, vy, vz;
    if (p2 <= 0.0) {
        vx = 0.0; vy = 0.0; vz = 1.0;  // exactly isotropic (won't happen with random data)
    } else {
        const double p = sqrt(p2 / 6.0);
        const double ip = 1.0 / p;
        const double c00 = b00 * ip, c11 = b11 * ip, c22 = b22 * ip;
        const double c01 = a01 * ip, c02 = a02 * ip, c12 = a12 * ip;
        double r = 0.5 * (c00 * (c11 * c22 - c12 * c12)
                        - c01 * (c01 * c22 - c12 * c02)
                        + c02 * (c01 * c12 - c11 * c02));
        r = fmin(1.0, fmax(-1.0, r));
        const double phi = acos(r) / 3.0;
        const double lam = q + 2.0 * p * cos(phi);  // largest eigenvalue

        // Eigenvector: max-norm cross product of rows of (A - lam*I).
        const double r0x = a00 - lam, r0y = a01, r0z = a02;
        const double r1x = a01, r1y = a11 - lam, r1z = a12;
        const double r2x = a02, r2y = a12, r2z = a22 - lam;

        double cx0 = r0y * r1z - r0z * r1y, cy0 = r0z * r1x - r0x * r1z, cz0 = r0x * r1y - r0y * r1x;
        double cx1 = r0y * r2z - r0z * r2y, cy1 = r0z * r2x - r0x * r2z, cz1 = r0x * r2y - r0y * r2x;
        double cx2 = r1y * r2z - r1z * r2y, cy2 = r1z * r2x - r1x * r2z, cz2 = r1x * r2y - r1y * r2x;
        const double n0 = cx0 * cx0 + cy0 * cy0 + cz0 * cz0;
        const double n1 = cx1 * cx1 + cy1 * cy1 + cz1 * cz1;
        const double n2 = cx2 * cx2 + cy2 * cy2 + cz2 * cz2;

        double bx, by, bz, bn;
        if (n0 >= n1 && n0 >= n2)      { bx = cx0; by = cy0; bz = cz0; bn = n0; }
        else if (n1 >= n2)             { bx = cx1; by = cy1; bz = cz1; bn = n1; }
        else                           { bx = cx2; by = cy2; bz = cz2; bn = n2; }
        const double inv = 1.0 / sqrt(bn);
        vx = bx * inv; vy = by * inv; vz = bz * inv;
    }

    // ZFwd = quat_vec_mul(Qrot, (0,0,1)) with Qrot = x[3:7, 0] (Unity x,y,z,w).
    const double qx = (double)x[3 * (size_t)T_LEN];
    const double qy = (double)x[4 * (size_t)T_LEN];
    const double qz = (double)x[5 * (size_t)T_LEN];
    const double qw = (double)x[6 * (size_t)T_LEN];
    const double zfx = 2.0 * (qx * qz + qw * qy);
    const double zfy = 2.0 * (qy * qz - qw * qx);
    const double zfz = 1.0 - 2.0 * (qx * qx + qy * qy);
    if (zfx * vx + zfy * vy + zfz * vz < 0.0) { vx = -vx; vy = -vy; vz = -vz; }

    const double ux = (double)ref_axis[0], uy = (double)ref_axis[1], uz = (double)ref_axis[2];
    // new_right = cross(up, pca_z)
    const double rx = uy * vz - uz * vy;
    const double ry = uz * vx - ux * vz;
    const double rz = ux * vy - uy * vx;
    // new_fwd = cross(new_right, up)
    const double fx = ry * uz - rz * uy;
    const double fy = rz * ux - rx * uz;
    const double fz = rx * uy - ry * ux;

    bp[0] = (float)rx; bp[1] = (float)ry; bp[2] = (float)rz;
    bp[3] = (float)ux; bp[4] = (float)uy; bp[5] = (float)uz;
    bp[6] = (float)fx; bp[7] = (float)fy; bp[8] = (float)fz;
    bp[9]  = x[0];
    bp[10] = x[(size_t)T_LEN];
    bp[11] = x[2 * (size_t)T_LEN];
}

// ---------------------------------------------------------------------------
// Pass 3: out[0:3T) = basis @ (Xpos - refPos); out[3T:6T) = rows 7..9 copy.
// Pure streaming: 96 MB read + 96 MB write, float4 throughout.
// ---------------------------------------------------------------------------
__global__ void transform_kernel(const float* __restrict__ x,
                                 const float* __restrict__ bp,
                                 float* __restrict__ out) {
    __shared__ float sb[12];
    if (threadIdx.x < 12) sb[threadIdx.x] = bp[threadIdx.x];
    __syncthreads();
    const float B00 = sb[0], B01 = sb[1], B02 = sb[2];
    const float B10 = sb[3], B11 = sb[4], B12 = sb[5];
    const float B20 = sb[6], B21 = sb[7], B22 = sb[8];
    const float p0 = sb[9], p1 = sb[10], p2 = sb[11];

    const float4* __restrict__ r0 = reinterpret_cast<const float4*>(x);
    const float4* __restrict__ r1 = reinterpret_cast<const float4*>(x + (size_t)T_LEN);
    const float4* __restrict__ r2 = reinterpret_cast<const float4*>(x + 2 * (size_t)T_LEN);
    const float4* __restrict__ r7 = reinterpret_cast<const float4*>(x + 7 * (size_t)T_LEN);
    const float4* __restrict__ r8 = reinterpret_cast<const float4*>(x + 8 * (size_t)T_LEN);
    const float4* __restrict__ r9 = reinterpret_cast<const float4*>(x + 9 * (size_t)T_LEN);
    float4* __restrict__ o0 = reinterpret_cast<float4*>(out);
    float4* __restrict__ o1 = reinterpret_cast<float4*>(out + (size_t)T_LEN);
    float4* __restrict__ o2 = reinterpret_cast<float4*>(out + 2 * (size_t)T_LEN);
    float4* __restrict__ o3 = reinterpret_cast<float4*>(out + 3 * (size_t)T_LEN);
    float4* __restrict__ o4 = reinterpret_cast<float4*>(out + 4 * (size_t)T_LEN);
    float4* __restrict__ o5 = reinterpret_cast<float4*>(out + 5 * (size_t)T_LEN);

    const int stride = gridDim.x * blockDim.x;
    for (int i = blockIdx.x * blockDim.x + threadIdx.x; i < T4; i += stride) {
        float4 a = r0[i];
        float4 b = r1[i];
        float4 c = r2[i];
        float4 u, v, w;

        float ax = a.x - p0, bx = b.x - p1, cx = c.x - p2;
        u.x = B00 * ax + B01 * bx + B02 * cx;
        v.x = B10 * ax + B11 * bx + B12 * cx;
        w.x = B20 * ax + B21 * bx + B22 * cx;

        float ay = a.y - p0, by = b.y - p1, cy = c.y - p2;
        u.y = B00 * ay + B01 * by + B02 * cy;
        v.y = B10 * ay + B11 * by + B12 * cy;
        w.y = B20 * ay + B21 * by + B22 * cy;

        float az = a.z - p0, bz = b.z - p1, cz = c.z - p2;
        u.z = B00 * az + B01 * bz + B02 * cz;
        v.z = B10 * az + B11 * bz + B12 * cz;
        w.z = B20 * az + B21 * bz + B22 * cz;

        float aw = a.w - p0, bw = b.w - p1, cw = c.w - p2;
        u.w = B00 * aw + B01 * bw + B02 * cw;
        v.w = B10 * aw + B11 * bw + B12 * cw;
        w.w = B20 * aw + B21 * bw + B22 * cw;

        o0[i] = u;
        o1[i] = v;
        o2[i] = w;
        o3[i] = r7[i];
        o4[i] = r8[i];
        o5[i] = r9[i];
    }
}

extern "C" void kernel_launch(void* const* d_in, const int* in_sizes, int n_in,
                              void* d_out, int out_size, void* d_ws, size_t ws_size,
                              hipStream_t stream) {
    const float* x = (const float*)d_in[0];        // (1,10,T) f32 flat, row f at f*T
    const float* ref_axis = (const float*)d_in[1]; // (3,) f32
    float* out = (float*)d_out;                    // (2,3,T) f32 flat

    double* sums = (double*)d_ws;
    float* bp = (float*)((char*)d_ws + 9 * sizeof(double));

    hipMemsetAsync(d_ws, 0, 9 * sizeof(double), stream);

    stats_kernel<<<1024, 256, 0, stream>>>(x, sums);
    finalize_kernel<<<1, 64, 0, stream>>>(x, ref_axis, sums, bp);

    const int blocks = (T4 + 255) / 256;
    transform_kernel<<<blocks, 256, 0, stream>>>(x, bp, out);
}

// Round 2
// 246.258 us; speedup vs baseline: 1.3982x; 1.3982x over previous
//
#include <hip/hip_runtime.h>

#define T_LEN 4000000
#define T4 (T_LEN / 4)
#define STATS_BLOCKS 256

// ---------------------------------------------------------------------------
// Pass 1: statistics over the 3 position rows -> per-block partial sums.
// NAMED scalar f64 accumulators (a double s[9] array gets demoted to scratch
// -> 15x slowdown, seen R1: VGPR=28 + 116us). No atomics: each block writes
// its own 9-double slot; one-block pass 2 reduces them.
// ---------------------------------------------------------------------------
__global__ void stats_kernel(const float* __restrict__ x, double* __restrict__ partials) {
    const float4* __restrict__ r0 = reinterpret_cast<const float4*>(x);
    const float4* __restrict__ r1 = reinterpret_cast<const float4*>(x + (size_t)T_LEN);
    const float4* __restrict__ r2 = reinterpret_cast<const float4*>(x + 2 * (size_t)T_LEN);

    double s0 = 0, s1 = 0, s2 = 0, s3 = 0, s4 = 0, s5 = 0, s6 = 0, s7 = 0, s8 = 0;

    const int stride = gridDim.x * blockDim.x;
    for (int i = blockIdx.x * blockDim.x + threadIdx.x; i < T4; i += stride) {
        float4 a = r0[i];
        float4 b = r1[i];
        float4 c = r2[i];
        s0 += (double)(a.x + a.y + a.z + a.w);
        s1 += (double)(b.x + b.y + b.z + b.w);
        s2 += (double)(c.x + c.y + c.z + c.w);
        s3 += (double)(a.x * a.x + a.y * a.y + a.z * a.z + a.w * a.w);
        s4 += (double)(b.x * b.x + b.y * b.y + b.z * b.z + b.w * b.w);
        s5 += (double)(c.x * c.x + c.y * c.y + c.z * c.z + c.w * c.w);
        s6 += (double)(a.x * b.x + a.y * b.y + a.z * b.z + a.w * b.w);
        s7 += (double)(a.x * c.x + a.y * c.y + a.z * c.z + a.w * c.w);
        s8 += (double)(b.x * c.x + b.y * c.y + b.z * c.z + b.w * c.w);
    }

#define WAVE_RED(S) S += __shfl_down(S, off, 64)
#pragma unroll
    for (int off = 32; off > 0; off >>= 1) {
        WAVE_RED(s0); WAVE_RED(s1); WAVE_RED(s2);
        WAVE_RED(s3); WAVE_RED(s4); WAVE_RED(s5);
        WAVE_RED(s6); WAVE_RED(s7); WAVE_RED(s8);
    }

    __shared__ double lds[4][9];  // 256 threads = 4 waves
    const int lane = threadIdx.x & 63;
    const int wave = threadIdx.x >> 6;
    if (lane == 0) {
        lds[wave][0] = s0; lds[wave][1] = s1; lds[wave][2] = s2;
        lds[wave][3] = s3; lds[wave][4] = s4; lds[wave][5] = s5;
        lds[wave][6] = s6; lds[wave][7] = s7; lds[wave][8] = s8;
    }
    __syncthreads();
    if (threadIdx.x < 9) {
        int k = threadIdx.x;
        partials[(size_t)blockIdx.x * 9 + k] =
            lds[0][k] + lds[1][k] + lds[2][k] + lds[3][k];
    }
}

// ---------------------------------------------------------------------------
// Pass 2 (one block, 256 threads): reduce 256x9 partials, then thread 0 runs
// the eigen/basis finalize (f64) and writes basis+refPos to bp.
// ---------------------------------------------------------------------------
__global__ void reduce_finalize_kernel(const float* __restrict__ x,
                                       const float* __restrict__ ref_axis,
                                       const double* __restrict__ partials,
                                       float* __restrict__ bp) {
    const double* __restrict__ p = partials + (size_t)threadIdx.x * 9;
    double s0 = p[0], s1 = p[1], s2 = p[2], s3 = p[3], s4 = p[4],
           s5 = p[5], s6 = p[6], s7 = p[7], s8 = p[8];

#pragma unroll
    for (int off = 32; off > 0; off >>= 1) {
        WAVE_RED(s0); WAVE_RED(s1); WAVE_RED(s2);
        WAVE_RED(s3); WAVE_RED(s4); WAVE_RED(s5);
        WAVE_RED(s6); WAVE_RED(s7); WAVE_RED(s8);
    }

    __shared__ double lds[4][9];
    const int lane = threadIdx.x & 63;
    const int wave = threadIdx.x >> 6;
    if (lane == 0) {
        lds[wave][0] = s0; lds[wave][1] = s1; lds[wave][2] = s2;
        lds[wave][3] = s3; lds[wave][4] = s4; lds[wave][5] = s5;
        lds[wave][6] = s6; lds[wave][7] = s7; lds[wave][8] = s8;
    }
    __syncthreads();
    if (threadIdx.x != 0) return;

    const double S0 = lds[0][0] + lds[1][0] + lds[2][0] + lds[3][0];
    const double S1 = lds[0][1] + lds[1][1] + lds[2][1] + lds[3][1];
    const double S2 = lds[0][2] + lds[1][2] + lds[2][2] + lds[3][2];
    const double S3 = lds[0][3] + lds[1][3] + lds[2][3] + lds[3][3];
    const double S4 = lds[0][4] + lds[1][4] + lds[2][4] + lds[3][4];
    const double S5 = lds[0][5] + lds[1][5] + lds[2][5] + lds[3][5];
    const double S6 = lds[0][6] + lds[1][6] + lds[2][6] + lds[3][6];
    const double S7 = lds[0][7] + lds[1][7] + lds[2][7] + lds[3][7];
    const double S8 = lds[0][8] + lds[1][8] + lds[2][8] + lds[3][8];

    const double T = (double)T_LEN;
    const double mu0 = S0 / T, mu1 = S1 / T, mu2 = S2 / T;
    const double d = 1.0 / (T - 1.0);
    const double a00 = (S3 - T * mu0 * mu0) * d;
    const double a11 = (S4 - T * mu1 * mu1) * d;
    const double a22 = (S5 - T * mu2 * mu2) * d;
    const double a01 = (S6 - T * mu0 * mu1) * d;
    const double a02 = (S7 - T * mu0 * mu2) * d;
    const double a12 = (S8 - T * mu1 * mu2) * d;

    // Largest eigenvalue via trigonometric method (Smith), f64.
    const double q = (a00 + a11 + a22) / 3.0;
    const double p1 = a01 * a01 + a02 * a02 + a12 * a12;
    const double b00 = a00 - q, b11 = a11 - q, b22 = a22 - q;
    const double p2 = b00 * b00 + b11 * b11 + b22 * b22 + 2.0 * p1;

    double vx, vy, vz;
    if (p2 <= 0.0) {
        vx = 0.0; vy = 0.0; vz = 1.0;
    } else {
        const double pp = sqrt(p2 / 6.0);
        const double ip = 1.0 / pp;
        const double c00 = b00 * ip, c11 = b11 * ip, c22 = b22 * ip;
        const double c01 = a01 * ip, c02 = a02 * ip, c12 = a12 * ip;
        double r = 0.5 * (c00 * (c11 * c22 - c12 * c12)
                        - c01 * (c01 * c22 - c12 * c02)
                        + c02 * (c01 * c12 - c11 * c02));
        r = fmin(1.0, fmax(-1.0, r));
        const double phi = acos(r) / 3.0;
        const double lam = q + 2.0 * pp * cos(phi);  // largest eigenvalue

        // Eigenvector: max-norm cross product of rows of (A - lam*I).
        const double r0x = a00 - lam, r0y = a01, r0z = a02;
        const double r1x = a01, r1y = a11 - lam, r1z = a12;
        const double r2x = a02, r2y = a12, r2z = a22 - lam;

        double cx0 = r0y * r1z - r0z * r1y, cy0 = r0z * r1x - r0x * r1z, cz0 = r0x * r1y - r0y * r1x;
        double cx1 = r0y * r2z - r0z * r2y, cy1 = r0z * r2x - r0x * r2z, cz1 = r0x * r2y - r0y * r2x;
        double cx2 = r1y * r2z - r1z * r2y, cy2 = r1z * r2x - r1x * r2z, cz2 = r1x * r2y - r1y * r2x;
        const double n0 = cx0 * cx0 + cy0 * cy0 + cz0 * cz0;
        const double n1 = cx1 * cx1 + cy1 * cy1 + cz1 * cz1;
        const double n2 = cx2 * cx2 + cy2 * cy2 + cz2 * cz2;

        double bx, by, bz, bn;
        if (n0 >= n1 && n0 >= n2)      { bx = cx0; by = cy0; bz = cz0; bn = n0; }
        else if (n1 >= n2)             { bx = cx1; by = cy1; bz = cz1; bn = n1; }
        else                           { bx = cx2; by = cy2; bz = cz2; bn = n2; }
        const double inv = 1.0 / sqrt(bn);
        vx = bx * inv; vy = by * inv; vz = bz * inv;
    }

    // ZFwd = quat_vec_mul(Qrot, (0,0,1)), Qrot = x[3:7, 0] (Unity x,y,z,w).
    const double qx = (double)x[3 * (size_t)T_LEN];
    const double qy = (double)x[4 * (size_t)T_LEN];
    const double qz = (double)x[5 * (size_t)T_LEN];
    const double qw = (double)x[6 * (size_t)T_LEN];
    const double zfx = 2.0 * (qx * qz + qw * qy);
    const double zfy = 2.0 * (qy * qz - qw * qx);
    const double zfz = 1.0 - 2.0 * (qx * qx + qy * qy);
    if (zfx * vx + zfy * vy + zfz * vz < 0.0) { vx = -vx; vy = -vy; vz = -vz; }

    const double ux = (double)ref_axis[0], uy = (double)ref_axis[1], uz = (double)ref_axis[2];
    // new_right = cross(up, pca_z)
    const double rx = uy * vz - uz * vy;
    const double ry = uz * vx - ux * vz;
    const double rz = ux * vy - uy * vx;
    // new_fwd = cross(new_right, up)
    const double fx = ry * uz - rz * uy;
    const double fy = rz * ux - rx * uz;
    const double fz = rx * uy - ry * ux;

    bp[0] = (float)rx; bp[1] = (float)ry; bp[2] = (float)rz;
    bp[3] = (float)ux; bp[4] = (float)uy; bp[5] = (float)uz;
    bp[6] = (float)fx; bp[7] = (float)fy; bp[8] = (float)fz;
    bp[9]  = x[0];
    bp[10] = x[(size_t)T_LEN];
    bp[11] = x[2 * (size_t)T_LEN];
}

// ---------------------------------------------------------------------------
// Pass 3: out[0:3T) = basis @ (Xpos - refPos); out[3T:6T) = rows 7..9 copy.
// Pure streaming: 96 MB read + 96 MB write, float4 throughout.
// ---------------------------------------------------------------------------
__global__ void transform_kernel(const float* __restrict__ x,
                                 const float* __restrict__ bp,
                                 float* __restrict__ out) {
    __shared__ float sb[12];
    if (threadIdx.x < 12) sb[threadIdx.x] = bp[threadIdx.x];
    __syncthreads();
    const float B00 = sb[0], B01 = sb[1], B02 = sb[2];
    const float B10 = sb[3], B11 = sb[4], B12 = sb[5];
    const float B20 = sb[6], B21 = sb[7], B22 = sb[8];
    const float p0 = sb[9], p1 = sb[10], p2 = sb[11];

    const float4* __restrict__ r0 = reinterpret_cast<const float4*>(x);
    const float4* __restrict__ r1 = reinterpret_cast<const float4*>(x + (size_t)T_LEN);
    const float4* __restrict__ r2 = reinterpret_cast<const float4*>(x + 2 * (size_t)T_LEN);
    const float4* __restrict__ r7 = reinterpret_cast<const float4*>(x + 7 * (size_t)T_LEN);
    const float4* __restrict__ r8 = reinterpret_cast<const float4*>(x + 8 * (size_t)T_LEN);
    const float4* __restrict__ r9 = reinterpret_cast<const float4*>(x + 9 * (size_t)T_LEN);
    float4* __restrict__ o0 = reinterpret_cast<float4*>(out);
    float4* __restrict__ o1 = reinterpret_cast<float4*>(out + (size_t)T_LEN);
    float4* __restrict__ o2 = reinterpret_cast<float4*>(out + 2 * (size_t)T_LEN);
    float4* __restrict__ o3 = reinterpret_cast<float4*>(out + 3 * (size_t)T_LEN);
    float4* __restrict__ o4 = reinterpret_cast<float4*>(out + 4 * (size_t)T_LEN);
    float4* __restrict__ o5 = reinterpret_cast<float4*>(out + 5 * (size_t)T_LEN);

    const int stride = gridDim.x * blockDim.x;
    for (int i = blockIdx.x * blockDim.x + threadIdx.x; i < T4; i += stride) {
        float4 a = r0[i];
        float4 b = r1[i];
        float4 c = r2[i];
        float4 u, v, w;

        float ax = a.x - p0, bx = b.x - p1, cx = c.x - p2;
        u.x = B00 * ax + B01 * bx + B02 * cx;
        v.x = B10 * ax + B11 * bx + B12 * cx;
        w.x = B20 * ax + B21 * bx + B22 * cx;

        float ay = a.y - p0, by = b.y - p1, cy = c.y - p2;
        u.y = B00 * ay + B01 * by + B02 * cy;
        v.y = B10 * ay + B11 * by + B12 * cy;
        w.y = B20 * ay + B21 * by + B22 * cy;

        float az = a.z - p0, bz = b.z - p1, cz = c.z - p2;
        u.z = B00 * az + B01 * bz + B02 * cz;
        v.z = B10 * az + B11 * bz + B12 * cz;
        w.z = B20 * az + B21 * bz + B22 * cz;

        float aw = a.w - p0, bw = b.w - p1, cw = c.w - p2;
        u.w = B00 * aw + B01 * bw + B02 * cw;
        v.w = B10 * aw + B11 * bw + B12 * cw;
        w.w = B20 * aw + B21 * bw + B22 * cw;

        o0[i] = u;
        o1[i] = v;
        o2[i] = w;
        o3[i] = r7[i];
        o4[i] = r8[i];
        o5[i] = r9[i];
    }
}

extern "C" void kernel_launch(void* const* d_in, const int* in_sizes, int n_in,
                              void* d_out, int out_size, void* d_ws, size_t ws_size,
                              hipStream_t stream) {
    const float* x = (const float*)d_in[0];        // (1,10,T) f32 flat, row f at f*T
    const float* ref_axis = (const float*)d_in[1]; // (3,) f32
    float* out = (float*)d_out;                    // (2,3,T) f32 flat

    double* partials = (double*)d_ws;                                  // 256*9 doubles = 18 KB
    float* bp = (float*)((char*)d_ws + STATS_BLOCKS * 9 * sizeof(double));

    stats_kernel<<<STATS_BLOCKS, 256, 0, stream>>>(x, partials);
    reduce_finalize_kernel<<<1, 256, 0, stream>>>(x, ref_axis, partials, bp);

    const int blocks = (T4 + 255) / 256;
    transform_kernel<<<blocks, 256, 0, stream>>>(x, bp, out);
}